// Round 1
// baseline (3433.729 us; speedup 1.0000x reference)
//
#include <hip/hip_runtime.h>
#include <hip/hip_bf16.h>
#include <stdint.h>

// ---------------- problem constants (fixed by setup_inputs) ----------------
#define DIMC   4096
#define HC     32
#define DC     128
#define TPC    2048      // prefill tokens
#define TOKC   2056      // total tokens
#define BDC    8         // decode batch
#define MAXBC  64        // blocks per decode seq
#define PSEQC  1024      // prefill seq len (2 seqs)
#define QKVN   12288     // 3*H*D
#define FFNC   16384     // 4*DIM
#define PSCALE 0.08838834764831843f  // 1/sqrt(128)

typedef __attribute__((ext_vector_type(8))) short short8;
typedef __attribute__((ext_vector_type(4))) float f32x4;
typedef __attribute__((ext_vector_type(4))) unsigned short u16x4;
typedef __attribute__((ext_vector_type(8))) unsigned short u16x8;

__device__ inline unsigned short f2bf(float f) {   // f32 -> bf16 RNE
  union { float f; unsigned u; } v; v.f = f;
  unsigned r = v.u + 0x7FFFu + ((v.u >> 16) & 1u);
  return (unsigned short)(r >> 16);
}
__device__ inline float bf2f(unsigned short u) {
  union { unsigned u; float f; } v; v.u = ((unsigned)u) << 16;
  return v.f;
}
__device__ inline f32x4 mfma16(short8 a, short8 b, f32x4 c) {
  return __builtin_amdgcn_mfma_f32_16x16x32_bf16(a, b, c, 0, 0, 0);
}

// ---------------- RMSNorm: f32 in -> bf16 out ----------------
__global__ __launch_bounds__(256) void rmsnorm_k(
    const float* __restrict__ x, const float* __restrict__ w,
    unsigned short* __restrict__ out)
{
  const int row = blockIdx.x;
  const int tid = threadIdx.x;
  const f32x4* xr = (const f32x4*)(x + (size_t)row * DIMC);
  f32x4 v[4];
  float ss = 0.f;
#pragma unroll
  for (int i = 0; i < 4; ++i) {
    v[i] = xr[i * 256 + tid];
    ss += v[i][0]*v[i][0] + v[i][1]*v[i][1] + v[i][2]*v[i][2] + v[i][3]*v[i][3];
  }
  for (int off = 32; off; off >>= 1) ss += __shfl_xor(ss, off);
  __shared__ float sred[4];
  if ((tid & 63) == 0) sred[tid >> 6] = ss;
  __syncthreads();
  const float rms = rsqrtf((sred[0]+sred[1]+sred[2]+sred[3]) * (1.f/DIMC) + 1e-5f);
  const f32x4* wr = (const f32x4*)w;
#pragma unroll
  for (int i = 0; i < 4; ++i) {
    f32x4 wv = wr[i * 256 + tid];
    u16x4 o;
#pragma unroll
    for (int j = 0; j < 4; ++j) o[j] = f2bf(v[i][j] * rms * wv[j]);
    *(u16x4*)(out + (size_t)row * DIMC + (size_t)(i * 256 + tid) * 4) = o;
  }
}

// ---------------- GEMM: C[M,N] = A_bf16[M,K] @ B_f32[N,K]^T (+Res) ----------
// MODE 1: f32 out + Res ; MODE 2: bf16 out, no Res
// 128x128 tile, BK=64, 4 waves (each 64x64 = 4x4 frags of 16x16x32 MFMA).
// LDS XOR swizzle (row&7)<<4 on byte addr, applied on BOTH write and read.
template<int MODE>
__global__ __launch_bounds__(256) void gemm_bt(
    const unsigned short* __restrict__ A, const float* __restrict__ B,
    float* __restrict__ Cf, unsigned short* __restrict__ Cb,
    const float* __restrict__ Res, int M, int N, int K)
{
  __shared__ unsigned short la[128 * 64];
  __shared__ unsigned short lb[128 * 64];
  const int tid = threadIdx.x;
  const int lane = tid & 63, wid = tid >> 6;
  const int wr = wid >> 1, wc = wid & 1;
  const int lhi = lane >> 4, llo = lane & 15;
  const int bm = blockIdx.y * 128, bn = blockIdx.x * 128;

  f32x4 acc[4][4] = {};

  for (int k0 = 0; k0 < K; k0 += 64) {
    // stage A (bf16, clamp M edge: clamped rows feed only unwritten outputs)
#pragma unroll
    for (int p = 0; p < 4; ++p) {
      int idx = p * 256 + tid;
      int row = idx >> 3, c8 = (idx & 7) << 3;
      int gr = bm + row; gr = gr < M ? gr : M - 1;
      short8 av = *(const short8*)(A + (size_t)gr * K + k0 + c8);
      int byt = (row << 7) + (c8 << 1);
      byt ^= (row & 7) << 4;
      *(short8*)((char*)la + byt) = av;
    }
    // stage B (f32 -> bf16 convert; N always multiple of 128 here)
#pragma unroll
    for (int p = 0; p < 4; ++p) {
      int idx = p * 256 + tid;
      int row = idx >> 3, c8 = (idx & 7) << 3;
      const float* src = B + (size_t)(bn + row) * K + k0 + c8;
      f32x4 b0 = *(const f32x4*)src;
      f32x4 b1 = *(const f32x4*)(src + 4);
      short8 bv;
#pragma unroll
      for (int i = 0; i < 4; ++i) { bv[i] = (short)f2bf(b0[i]); bv[i+4] = (short)f2bf(b1[i]); }
      int byt = (row << 7) + (c8 << 1);
      byt ^= (row & 7) << 4;
      *(short8*)((char*)lb + byt) = bv;
    }
    __syncthreads();
#pragma unroll
    for (int kk = 0; kk < 64; kk += 32) {
      short8 af[4], bfr[4];
#pragma unroll
      for (int m = 0; m < 4; ++m) {
        int row = wr * 64 + m * 16 + llo;
        int byt = (row << 7) + ((kk + lhi * 8) << 1);
        byt ^= (row & 7) << 4;
        af[m] = *(const short8*)((const char*)la + byt);
      }
#pragma unroll
      for (int n = 0; n < 4; ++n) {
        int row = wc * 64 + n * 16 + llo;
        int byt = (row << 7) + ((kk + lhi * 8) << 1);
        byt ^= (row & 7) << 4;
        bfr[n] = *(const short8*)((const char*)lb + byt);
      }
#pragma unroll
      for (int m = 0; m < 4; ++m)
#pragma unroll
        for (int n = 0; n < 4; ++n)
          acc[m][n] = mfma16(af[m], bfr[n], acc[m][n]);
    }
    __syncthreads();
  }

  // epilogue: C/D layout col=lane&15, row=(lane>>4)*4+reg
#pragma unroll
  for (int m = 0; m < 4; ++m) {
#pragma unroll
    for (int j = 0; j < 4; ++j) {
      int row = bm + wr * 64 + m * 16 + lhi * 4 + j;
      if (row < M) {
#pragma unroll
        for (int n = 0; n < 4; ++n) {
          int col = bn + wc * 64 + n * 16 + llo;
          float v = acc[m][n][j];
          if (MODE == 1) {
            v += Res[(size_t)row * N + col];
            Cf[(size_t)row * N + col] = v;
          } else {
            Cb[(size_t)row * N + col] = f2bf(v);
          }
        }
      }
    }
  }
}

// ---------------- Prefill flash attention (causal, per-seq) ----------------
// grid (H, PSEQ/64, 2). Block: 4 waves; wave w owns q rows q0+w*16..+16.
// Q frags in regs; K reg-staged to LDS (element-XOR swizzle (row&7)<<3);
// V transpose-staged to LDS (j-block XOR with (d>>3)&7); online softmax.
__global__ __launch_bounds__(256) void prefill_attn(
    const unsigned short* __restrict__ qkv, unsigned short* __restrict__ attnb)
{
  const int h = blockIdx.x, qt = blockIdx.y, s = blockIdx.z;
  const int seq0 = s * PSEQC;
  const int q0 = qt * 64;
  const int tid = threadIdx.x;
  const int lane = tid & 63, w = tid >> 6;
  const int lhi = lane >> 4, llo = lane & 15;

  __shared__ unsigned short lk[64 * 128];
  __shared__ unsigned short lvt[128 * 72];
  __shared__ unsigned short lp[4][16 * 72];

  short8 qf[4];
  {
    const unsigned short* qrow =
        qkv + (size_t)(seq0 + q0 + w * 16 + llo) * QKVN + h * DC;
#pragma unroll
    for (int kk = 0; kk < 4; ++kk)
      qf[kk] = *(const short8*)(qrow + kk * 32 + lhi * 8);
  }

  float m_r[4], l_r[4];
#pragma unroll
  for (int r = 0; r < 4; ++r) { m_r[r] = -1e30f; l_r[r] = 0.f; }
  f32x4 oacc[8] = {};

  const int ntiles = qt + 1;
  for (int t = 0; t < ntiles; ++t) {
    const int j0 = t * 64;
    // stage K tile (swizzled rows)
#pragma unroll
    for (int p = 0; p < 4; ++p) {
      int idx = p * 256 + tid;
      int row = idx >> 4, c8 = (idx & 15) << 3;
      short8 kv = *(const short8*)(qkv + (size_t)(seq0 + j0 + row) * QKVN + DIMC + h * DC + c8);
      *(short8*)(lk + row * 128 + (c8 ^ ((row & 7) << 3))) = kv;
    }
    // stage V^T (scalar, d-dependent j-block swizzle)
#pragma unroll
    for (int p = 0; p < 4; ++p) {
      int idx = p * 256 + tid;
      int j = idx >> 4, c8 = (idx & 15) << 3;
      short8 vv = *(const short8*)(qkv + (size_t)(seq0 + j0 + j) * QKVN + 2 * DIMC + h * DC + c8);
#pragma unroll
      for (int i = 0; i < 8; ++i) {
        int d = c8 + i;
        int jj = j ^ (((d >> 3) & 7) << 3);
        lvt[d * 72 + jj] = (unsigned short)vv[i];
      }
    }
    __syncthreads();

    // S = Q K^T  (16 MFMA per wave)
    f32x4 sfr[4] = {};
#pragma unroll
    for (int n = 0; n < 4; ++n) {
      int row = n * 16 + llo;
#pragma unroll
      for (int kk = 0; kk < 4; ++kk) {
        int col = (kk * 32 + lhi * 8) ^ ((row & 7) << 3);
        short8 kf = *(const short8*)(lk + row * 128 + col);
        sfr[n] = mfma16(qf[kk], kf, sfr[n]);
      }
    }

    // online softmax (C layout: row=(lhi*4+r), col=n*16+llo)
    const bool diag = (t == ntiles - 1);
    const int qbase = q0 + w * 16 + lhi * 4;
    float pv[4][4];
#pragma unroll
    for (int r = 0; r < 4; ++r) {
      float mx = -1e30f;
#pragma unroll
      for (int n = 0; n < 4; ++n) {
        float sv = sfr[n][r] * PSCALE;
        if (diag && (j0 + n * 16 + llo > qbase + r)) sv = -1e30f;
        pv[n][r] = sv;
        mx = fmaxf(mx, sv);
      }
      for (int off = 8; off; off >>= 1) mx = fmaxf(mx, __shfl_xor(mx, off));
      float mnew = fmaxf(m_r[r], mx);
      float alpha = __expf(m_r[r] - mnew);
      m_r[r] = mnew;
      float rs = 0.f;
#pragma unroll
      for (int n = 0; n < 4; ++n) {
        float p = __expf(pv[n][r] - mnew);
        pv[n][r] = p;
        rs += p;
      }
      for (int off = 8; off; off >>= 1) rs += __shfl_xor(rs, off);
      l_r[r] = l_r[r] * alpha + rs;
#pragma unroll
      for (int f = 0; f < 8; ++f) oacc[f][r] *= alpha;
    }

    // P -> LDS (wave-local buffer; in-wave LDS ordering suffices)
    unsigned short* lpw = lp[w];
#pragma unroll
    for (int r = 0; r < 4; ++r)
#pragma unroll
      for (int n = 0; n < 4; ++n)
        lpw[(lhi * 4 + r) * 72 + n * 16 + llo] = f2bf(pv[n][r]);

    // O += P @ V  (16 MFMA per wave)
#pragma unroll
    for (int kk = 0; kk < 2; ++kk) {
      short8 pf = *(const short8*)(lpw + llo * 72 + kk * 32 + lhi * 8);
#pragma unroll
      for (int f = 0; f < 8; ++f) {
        int d = f * 16 + llo;
        int jb = kk * 32 + lhi * 8;
        int jj = jb ^ (((d >> 3) & 7) << 3);
        short8 vf = *(const short8*)(lvt + d * 72 + jj);
        oacc[f] = mfma16(pf, vf, oacc[f]);
      }
    }
    __syncthreads();
  }

#pragma unroll
  for (int r = 0; r < 4; ++r) {
    int row = seq0 + q0 + w * 16 + lhi * 4 + r;
    float inv = 1.f / l_r[r];
#pragma unroll
    for (int f = 0; f < 8; ++f)
      attnb[(size_t)row * DIMC + h * DC + f * 16 + llo] = f2bf(oacc[f][r] * inv);
  }
}

// ---------------- Decode attention (paged KV, one block per (h,b)) ----------
// Heap scatter is NOT materialized: position ctx-1 is overridden with the
// fresh k/v from the qkv buffer (only the owning seq reads those slots).
__global__ __launch_bounds__(256) void decode_attn(
    const unsigned short* __restrict__ qkv,
    const float* __restrict__ kheap, const float* __restrict__ vheap,
    const int* __restrict__ btab, const int* __restrict__ ctxl,
    unsigned short* __restrict__ attnb)
{
  const int h = blockIdx.x, b = blockIdx.y;
  const int ctx = ctxl[b];
  const int tq = TPC + b;
  const int tid = threadIdx.x;
  __shared__ float sq[DC];
  __shared__ float sp[1024];
  __shared__ float sred[4];
  __shared__ float obuf[DC];

  const unsigned short* qrow = qkv + (size_t)tq * QKVN + h * DC;
  if (tid < DC) sq[tid] = bf2f(qrow[tid]);
  __syncthreads();

  float lmax = -1e30f;
#pragma unroll
  for (int i = 0; i < 4; ++i) {
    int l = i * 256 + tid;
    float sv = -1e30f;
    if (l < ctx) {
      float accd = 0.f;
      if (l == ctx - 1) {
        const unsigned short* kn = qkv + (size_t)tq * QKVN + DIMC + h * DC;
        for (int d = 0; d < DC; ++d) accd += sq[d] * bf2f(kn[d]);
      } else {
        int blk = btab[b * MAXBC + (l >> 4)];
        const float* kp = kheap + (((size_t)blk * 16 + (l & 15)) * HC + h) * DC;
#pragma unroll
        for (int d = 0; d < DC; d += 4) {
          f32x4 kv = *(const f32x4*)(kp + d);
          accd += sq[d] * kv[0] + sq[d+1] * kv[1] + sq[d+2] * kv[2] + sq[d+3] * kv[3];
        }
      }
      sv = accd * PSCALE;
    }
    sp[l] = sv;
    lmax = fmaxf(lmax, sv);
  }
  for (int off = 32; off; off >>= 1) lmax = fmaxf(lmax, __shfl_xor(lmax, off));
  if ((tid & 63) == 0) sred[tid >> 6] = lmax;
  __syncthreads();
  const float m = fmaxf(fmaxf(sred[0], sred[1]), fmaxf(sred[2], sred[3]));
  __syncthreads();  // everyone has read sred before reuse

  float lsum = 0.f;
#pragma unroll
  for (int i = 0; i < 4; ++i) {
    int l = i * 256 + tid;
    float p = __expf(sp[l] - m);   // -1e30 slots -> 0
    sp[l] = p;
    lsum += p;
  }
  for (int off = 32; off; off >>= 1) lsum += __shfl_xor(lsum, off);
  if ((tid & 63) == 0) sred[tid >> 6] = lsum;
  __syncthreads();
  const float denom = sred[0] + sred[1] + sred[2] + sred[3];

  const int d = tid & 127, half = tid >> 7;
  float o = 0.f;
  for (int l = half; l < ctx; l += 2) {
    float p = sp[l];
    float v;
    if (l == ctx - 1) {
      v = bf2f(qkv[(size_t)tq * QKVN + 2 * DIMC + h * DC + d]);
    } else {
      int blk = btab[b * MAXBC + (l >> 4)];
      v = vheap[(((size_t)blk * 16 + (l & 15)) * HC + h) * DC + d];
    }
    o += p * v;
  }
  if (half) obuf[d] = o;
  __syncthreads();
  if (!half)
    attnb[(size_t)tq * DIMC + h * DC + d] = f2bf((o + obuf[d]) / denom);
}

// ---------------- SiLU(g) * u : gu bf16 [T,32768] -> act bf16 [T,16384] -----
__global__ __launch_bounds__(256) void silu_mul(
    const unsigned short* __restrict__ gu, unsigned short* __restrict__ act)
{
  size_t chunk = (size_t)blockIdx.x * 256 + threadIdx.x;  // 2056*2048 chunks of 8
  size_t row = chunk >> 11;
  int c = (int)(chunk & 2047) << 3;
  const unsigned short* g = gu + row * (2 * FFNC) + c;
  u16x8 gv = *(const u16x8*)g;
  u16x8 uv = *(const u16x8*)(g + FFNC);
  u16x8 o;
#pragma unroll
  for (int i = 0; i < 8; ++i) {
    float gf = bf2f(gv[i]);
    float uf = bf2f(uv[i]);
    float sf = gf / (1.f + __expf(-gf));
    o[i] = f2bf(sf * uf);
  }
  *(u16x8*)(act + row * FFNC + c) = o;
}

// ---------------- launch ----------------
extern "C" void kernel_launch(void* const* d_in, const int* in_sizes, int n_in,
                              void* d_out, int out_size, void* d_ws, size_t ws_size,
                              hipStream_t stream) {
  const float* x     = (const float*)d_in[0];
  const float* kheap = (const float*)d_in[1];
  const float* vheap = (const float*)d_in[2];
  const int*   btab  = (const int*)d_in[4];
  const int*   ctxl  = (const int*)d_in[5];
  const float* n1w   = (const float*)d_in[10];
  const float* n2w   = (const float*)d_in[11];
  const float* wqkv  = (const float*)d_in[12];
  const float* wo    = (const float*)d_in[13];
  const float* wgu   = (const float*)d_in[14];
  const float* w2    = (const float*)d_in[15];
  float* out = (float*)d_out;

  // workspace layout (269,484,032 B total):
  //   xn   bf16 [TOK,4096]   (reused as xn2)
  //   qkv  bf16 [TOK,12288]  (region sized 67,371,008 B; reused as act [TOK,16384])
  //   attn bf16 [TOK,4096]
  //   h    f32  [TOK,4096]
  //   gu   bf16 [TOK,32768]
  char* ws = (char*)d_ws;
  unsigned short* xn   = (unsigned short*)(ws);
  unsigned short* qkvb = (unsigned short*)(ws + 16842752);
  unsigned short* actb = qkvb;  // alias: qkv dead after attention kernels
  unsigned short* attn = (unsigned short*)(ws + 16842752 + 67371008);
  float*          hbuf = (float*)(ws + 16842752 + 67371008 + 16842752);
  unsigned short* gub  = (unsigned short*)(ws + 16842752 + 67371008 + 16842752 + 33685504);

  // 1. xn = rmsnorm(x) * n1w
  rmsnorm_k<<<TOKC, 256, 0, stream>>>(x, n1w, xn);
  // 2. qkv = xn @ wqkv^T   (bf16 out)
  gemm_bt<2><<<dim3(QKVN / 128, 17), 256, 0, stream>>>(
      xn, wqkv, nullptr, qkvb, nullptr, TOKC, QKVN, DIMC);
  // 3. prefill attention (2 seqs x 1024, causal)
  prefill_attn<<<dim3(HC, PSEQC / 64, 2), 256, 0, stream>>>(qkvb, attn);
  // 4. decode attention (8 seqs, paged KV + fresh-kv override)
  decode_attn<<<dim3(HC, BDC), 256, 0, stream>>>(qkvb, kheap, vheap, btab, ctxl, attn);
  // 5. h = attn @ wo^T + x
  gemm_bt<1><<<dim3(DIMC / 128, 17), 256, 0, stream>>>(
      attn, wo, hbuf, nullptr, x, TOKC, DIMC, DIMC);
  // 6. xn2 = rmsnorm(h) * n2w
  rmsnorm_k<<<TOKC, 256, 0, stream>>>(hbuf, n2w, xn);
  // 7. gu = xn2 @ wgu^T  (bf16 out)
  gemm_bt<2><<<dim3(2 * FFNC / 128, 17), 256, 0, stream>>>(
      xn, wgu, nullptr, gub, nullptr, TOKC, 2 * FFNC, DIMC);
  // 8. act = silu(g) * u
  silu_mul<<<(TOKC * (FFNC / 8)) / 256, 256, 0, stream>>>(gub, actb);
  // 9. out = act @ w2^T + h
  gemm_bt<1><<<dim3(DIMC / 128, 17), 256, 0, stream>>>(
      actb, w2, out, nullptr, hbuf, TOKC, DIMC, FFNC);
}

// Round 2
// 2162.855 us; speedup vs baseline: 1.5876x; 1.5876x over previous
//
#include <hip/hip_runtime.h>
#include <hip/hip_bf16.h>
#include <stdint.h>

// ---------------- problem constants (fixed by setup_inputs) ----------------
#define DIMC   4096
#define HC     32
#define DC     128
#define TPC    2048      // prefill tokens
#define TOKC   2056      // total tokens
#define BDC    8         // decode batch
#define MAXBC  64        // blocks per decode seq
#define PSEQC  1024      // prefill seq len (2 seqs)
#define QKVN   12288     // 3*H*D
#define FFNC   16384     // 4*DIM
#define PSCALE 0.08838834764831843f  // 1/sqrt(128)

typedef __attribute__((ext_vector_type(8))) short short8;
typedef __attribute__((ext_vector_type(4))) float f32x4;
typedef __attribute__((ext_vector_type(4))) unsigned short u16x4;
typedef __attribute__((ext_vector_type(8))) unsigned short u16x8;

__device__ inline unsigned short f2bf(float f) {   // f32 -> bf16 RNE
  union { float f; unsigned u; } v; v.f = f;
  unsigned r = v.u + 0x7FFFu + ((v.u >> 16) & 1u);
  return (unsigned short)(r >> 16);
}
__device__ inline float bf2f(unsigned short u) {
  union { unsigned u; float f; } v; v.u = ((unsigned)u) << 16;
  return v.f;
}
__device__ inline f32x4 mfma16(short8 a, short8 b, f32x4 c) {
  return __builtin_amdgcn_mfma_f32_16x16x32_bf16(a, b, c, 0, 0, 0);
}
__device__ inline void gload16(const void* g, void* l) {
  __builtin_amdgcn_global_load_lds(
      (const __attribute__((address_space(1))) void*)g,
      (__attribute__((address_space(3))) void*)l, 16, 0, 0);
}

// ---------------- weight convert f32 -> bf16 (grid-stride, 8 elem/thread) ---
__global__ __launch_bounds__(256) void cvt_w(
    const float* __restrict__ in, unsigned short* __restrict__ out, long n8)
{
  long i = (long)blockIdx.x * 256 + threadIdx.x;
  const long stride = (long)gridDim.x * 256;
  for (; i < n8; i += stride) {
    f32x4 a = ((const f32x4*)in)[2 * i];
    f32x4 b = ((const f32x4*)in)[2 * i + 1];
    u16x8 o;
#pragma unroll
    for (int j = 0; j < 4; ++j) { o[j] = f2bf(a[j]); o[j + 4] = f2bf(b[j]); }
    ((u16x8*)out)[i] = o;
  }
}

// ---------------- RMSNorm: f32 in -> bf16 out ----------------
__global__ __launch_bounds__(256) void rmsnorm_k(
    const float* __restrict__ x, const float* __restrict__ w,
    unsigned short* __restrict__ out)
{
  const int row = blockIdx.x;
  const int tid = threadIdx.x;
  const f32x4* xr = (const f32x4*)(x + (size_t)row * DIMC);
  f32x4 v[4];
  float ss = 0.f;
#pragma unroll
  for (int i = 0; i < 4; ++i) {
    v[i] = xr[i * 256 + tid];
    ss += v[i][0]*v[i][0] + v[i][1]*v[i][1] + v[i][2]*v[i][2] + v[i][3]*v[i][3];
  }
  for (int off = 32; off; off >>= 1) ss += __shfl_xor(ss, off);
  __shared__ float sred[4];
  if ((tid & 63) == 0) sred[tid >> 6] = ss;
  __syncthreads();
  const float rms = rsqrtf((sred[0]+sred[1]+sred[2]+sred[3]) * (1.f/DIMC) + 1e-5f);
  const f32x4* wr = (const f32x4*)w;
#pragma unroll
  for (int i = 0; i < 4; ++i) {
    f32x4 wv = wr[i * 256 + tid];
    u16x4 o;
#pragma unroll
    for (int j = 0; j < 4; ++j) o[j] = f2bf(v[i][j] * rms * wv[j]);
    *(u16x4*)(out + (size_t)row * DIMC + (size_t)(i * 256 + tid) * 4) = o;
  }
}

// ---------------- GEMM: C[M,N] = A_bf16[M,K] @ B[N,K]^T (+Res) --------------
// MODE 1: f32 out + Res ; MODE 2: bf16 out, no Res
// BF16B 1: B already bf16 -> global_load_lds staging (pre-swizzled source)
// BF16B 0: B f32 -> register staging with f32->bf16 convert (fallback)
// 128x128 tile, BK=64, 4 waves. LDS XOR swizzle (row&7)<<4 on byte addr.
// 1-D grid, M-fast tile order + bijective XCD chunking (B-panel L2 reuse).
template<int MODE, int BF16B>
__global__ __launch_bounds__(256) void gemm_bt(
    const unsigned short* __restrict__ A, const float* __restrict__ Bf,
    const unsigned short* __restrict__ Bh,
    float* __restrict__ Cf, unsigned short* __restrict__ Cb,
    const float* __restrict__ Res, int M, int N, int K)
{
  __shared__ unsigned short la[128 * 64];
  __shared__ unsigned short lb[128 * 64];
  const int tid = threadIdx.x;
  const int lane = tid & 63, wid = tid >> 6;
  const int wr = wid >> 1, wc = wid & 1;
  const int lhi = lane >> 4, llo = lane & 15;

  // tile id: bijective XCD swizzle (m204), then M-fast decomposition
  const int nM = (M + 127) >> 7;
  const int nwg = gridDim.x;
  const int orig = blockIdx.x;
  const int qq = nwg >> 3, rr = nwg & 7;
  const int xcd = orig & 7, lid = orig >> 3;
  const int wgid = (xcd < rr ? xcd * (qq + 1) : rr * (qq + 1) + (xcd - rr) * qq) + lid;
  const int bm = (wgid % nM) * 128;
  const int bn = (wgid / nM) * 128;

  // staging sources: LDS kept linear in slot order; global source pre-swizzled
  // (slot s holds element chunk (s&7)^(row&7) of row s>>3 -> read XOR matches)
  const unsigned short* aSrc[4];
  const unsigned short* bSrcH[4];
  char* aDst[4];
  char* bDst[4];
#pragma unroll
  for (int p = 0; p < 4; ++p) {
    int slot = p * 256 + tid;
    int row = slot >> 3;
    int chunk = (slot & 7) ^ (row & 7);
    int gr = bm + row; gr = gr < M ? gr : M - 1;   // clamped rows feed unwritten outputs
    aSrc[p] = A + (size_t)gr * K + chunk * 8;
    aDst[p] = (char*)la + p * 4096 + wid * 1024;
    if (BF16B) {
      bSrcH[p] = Bh + (size_t)(bn + row) * K + chunk * 8;
      bDst[p] = (char*)lb + p * 4096 + wid * 1024;
    }
  }

  f32x4 acc[4][4] = {};

  for (int k0 = 0; k0 < K; k0 += 64) {
#pragma unroll
    for (int p = 0; p < 4; ++p) gload16(aSrc[p] + k0, aDst[p]);
    if (BF16B) {
#pragma unroll
      for (int p = 0; p < 4; ++p) gload16(bSrcH[p] + k0, bDst[p]);
    } else {
#pragma unroll
      for (int p = 0; p < 4; ++p) {
        int idx = p * 256 + tid;
        int row = idx >> 3, c8 = (idx & 7) << 3;
        const float* src = Bf + (size_t)(bn + row) * K + k0 + c8;
        f32x4 b0 = *(const f32x4*)src;
        f32x4 b1 = *(const f32x4*)(src + 4);
        short8 bv;
#pragma unroll
        for (int i = 0; i < 4; ++i) { bv[i] = (short)f2bf(b0[i]); bv[i+4] = (short)f2bf(b1[i]); }
        int byt = (row << 7) + (c8 << 1);
        byt ^= (row & 7) << 4;
        *(short8*)((char*)lb + byt) = bv;
      }
    }
    __syncthreads();
#pragma unroll
    for (int kk = 0; kk < 64; kk += 32) {
      short8 af[4], bfr[4];
#pragma unroll
      for (int m = 0; m < 4; ++m) {
        int row = wr * 64 + m * 16 + llo;
        int byt = (row << 7) + ((kk + lhi * 8) << 1);
        byt ^= (row & 7) << 4;
        af[m] = *(const short8*)((const char*)la + byt);
      }
#pragma unroll
      for (int n = 0; n < 4; ++n) {
        int row = wc * 64 + n * 16 + llo;
        int byt = (row << 7) + ((kk + lhi * 8) << 1);
        byt ^= (row & 7) << 4;
        bfr[n] = *(const short8*)((const char*)lb + byt);
      }
#pragma unroll
      for (int m = 0; m < 4; ++m)
#pragma unroll
        for (int n = 0; n < 4; ++n)
          acc[m][n] = mfma16(af[m], bfr[n], acc[m][n]);
    }
    __syncthreads();
  }

  // epilogue: C/D layout col=lane&15, row=(lane>>4)*4+reg
#pragma unroll
  for (int m = 0; m < 4; ++m) {
#pragma unroll
    for (int j = 0; j < 4; ++j) {
      int row = bm + wr * 64 + m * 16 + lhi * 4 + j;
      if (row < M) {
#pragma unroll
        for (int n = 0; n < 4; ++n) {
          int col = bn + wc * 64 + n * 16 + llo;
          float v = acc[m][n][j];
          if (MODE == 1) {
            v += Res[(size_t)row * N + col];
            Cf[(size_t)row * N + col] = v;
          } else {
            Cb[(size_t)row * N + col] = f2bf(v);
          }
        }
      }
    }
  }
}

// ---------------- Prefill flash attention (causal, per-seq) ----------------
__global__ __launch_bounds__(256) void prefill_attn(
    const unsigned short* __restrict__ qkv, unsigned short* __restrict__ attnb)
{
  const int h = blockIdx.x, qt = blockIdx.y, s = blockIdx.z;
  const int seq0 = s * PSEQC;
  const int q0 = qt * 64;
  const int tid = threadIdx.x;
  const int lane = tid & 63, w = tid >> 6;
  const int lhi = lane >> 4, llo = lane & 15;

  __shared__ unsigned short lk[64 * 128];
  __shared__ unsigned short lvt[128 * 72];
  __shared__ unsigned short lp[4][16 * 72];

  short8 qf[4];
  {
    const unsigned short* qrow =
        qkv + (size_t)(seq0 + q0 + w * 16 + llo) * QKVN + h * DC;
#pragma unroll
    for (int kk = 0; kk < 4; ++kk)
      qf[kk] = *(const short8*)(qrow + kk * 32 + lhi * 8);
  }

  float m_r[4], l_r[4];
#pragma unroll
  for (int r = 0; r < 4; ++r) { m_r[r] = -1e30f; l_r[r] = 0.f; }
  f32x4 oacc[8] = {};

  const int ntiles = qt + 1;
  for (int t = 0; t < ntiles; ++t) {
    const int j0 = t * 64;
#pragma unroll
    for (int p = 0; p < 4; ++p) {
      int idx = p * 256 + tid;
      int row = idx >> 4, c8 = (idx & 15) << 3;
      short8 kv = *(const short8*)(qkv + (size_t)(seq0 + j0 + row) * QKVN + DIMC + h * DC + c8);
      *(short8*)(lk + row * 128 + (c8 ^ ((row & 7) << 3))) = kv;
    }
#pragma unroll
    for (int p = 0; p < 4; ++p) {
      int idx = p * 256 + tid;
      int j = idx >> 4, c8 = (idx & 15) << 3;
      short8 vv = *(const short8*)(qkv + (size_t)(seq0 + j0 + j) * QKVN + 2 * DIMC + h * DC + c8);
#pragma unroll
      for (int i = 0; i < 8; ++i) {
        int d = c8 + i;
        int jj = j ^ (((d >> 3) & 7) << 3);
        lvt[d * 72 + jj] = (unsigned short)vv[i];
      }
    }
    __syncthreads();

    f32x4 sfr[4] = {};
#pragma unroll
    for (int n = 0; n < 4; ++n) {
      int row = n * 16 + llo;
#pragma unroll
      for (int kk = 0; kk < 4; ++kk) {
        int col = (kk * 32 + lhi * 8) ^ ((row & 7) << 3);
        short8 kf = *(const short8*)(lk + row * 128 + col);
        sfr[n] = mfma16(qf[kk], kf, sfr[n]);
      }
    }

    const bool diag = (t == ntiles - 1);
    const int qbase = q0 + w * 16 + lhi * 4;
    float pv[4][4];
#pragma unroll
    for (int r = 0; r < 4; ++r) {
      float mx = -1e30f;
#pragma unroll
      for (int n = 0; n < 4; ++n) {
        float sv = sfr[n][r] * PSCALE;
        if (diag && (j0 + n * 16 + llo > qbase + r)) sv = -1e30f;
        pv[n][r] = sv;
        mx = fmaxf(mx, sv);
      }
      for (int off = 8; off; off >>= 1) mx = fmaxf(mx, __shfl_xor(mx, off));
      float mnew = fmaxf(m_r[r], mx);
      float alpha = __expf(m_r[r] - mnew);
      m_r[r] = mnew;
      float rs = 0.f;
#pragma unroll
      for (int n = 0; n < 4; ++n) {
        float p = __expf(pv[n][r] - mnew);
        pv[n][r] = p;
        rs += p;
      }
      for (int off = 8; off; off >>= 1) rs += __shfl_xor(rs, off);
      l_r[r] = l_r[r] * alpha + rs;
#pragma unroll
      for (int f = 0; f < 8; ++f) oacc[f][r] *= alpha;
    }

    unsigned short* lpw = lp[w];
#pragma unroll
    for (int r = 0; r < 4; ++r)
#pragma unroll
      for (int n = 0; n < 4; ++n)
        lpw[(lhi * 4 + r) * 72 + n * 16 + llo] = f2bf(pv[n][r]);

#pragma unroll
    for (int kk = 0; kk < 2; ++kk) {
      short8 pf = *(const short8*)(lpw + llo * 72 + kk * 32 + lhi * 8);
#pragma unroll
      for (int f = 0; f < 8; ++f) {
        int d = f * 16 + llo;
        int jb = kk * 32 + lhi * 8;
        int jj = jb ^ (((d >> 3) & 7) << 3);
        short8 vf = *(const short8*)(lvt + d * 72 + jj);
        oacc[f] = mfma16(pf, vf, oacc[f]);
      }
    }
    __syncthreads();
  }

#pragma unroll
  for (int r = 0; r < 4; ++r) {
    int row = seq0 + q0 + w * 16 + lhi * 4 + r;
    float inv = 1.f / l_r[r];
#pragma unroll
    for (int f = 0; f < 8; ++f)
      attnb[(size_t)row * DIMC + h * DC + f * 16 + llo] = f2bf(oacc[f][r] * inv);
  }
}

// ---------------- Decode attention (paged KV, fresh-kv override) ------------
__global__ __launch_bounds__(256) void decode_attn(
    const unsigned short* __restrict__ qkv,
    const float* __restrict__ kheap, const float* __restrict__ vheap,
    const int* __restrict__ btab, const int* __restrict__ ctxl,
    unsigned short* __restrict__ attnb)
{
  const int h = blockIdx.x, b = blockIdx.y;
  const int ctx = ctxl[b];
  const int tq = TPC + b;
  const int tid = threadIdx.x;
  __shared__ float sq[DC];
  __shared__ float sp[1024];
  __shared__ float sred[4];
  __shared__ float obuf[DC];

  const unsigned short* qrow = qkv + (size_t)tq * QKVN + h * DC;
  if (tid < DC) sq[tid] = bf2f(qrow[tid]);
  __syncthreads();

  float lmax = -1e30f;
#pragma unroll
  for (int i = 0; i < 4; ++i) {
    int l = i * 256 + tid;
    float sv = -1e30f;
    if (l < ctx) {
      float accd = 0.f;
      if (l == ctx - 1) {
        const unsigned short* kn = qkv + (size_t)tq * QKVN + DIMC + h * DC;
        for (int d = 0; d < DC; ++d) accd += sq[d] * bf2f(kn[d]);
      } else {
        int blk = btab[b * MAXBC + (l >> 4)];
        const float* kp = kheap + (((size_t)blk * 16 + (l & 15)) * HC + h) * DC;
#pragma unroll
        for (int d = 0; d < DC; d += 4) {
          f32x4 kv = *(const f32x4*)(kp + d);
          accd += sq[d] * kv[0] + sq[d+1] * kv[1] + sq[d+2] * kv[2] + sq[d+3] * kv[3];
        }
      }
      sv = accd * PSCALE;
    }
    sp[l] = sv;
    lmax = fmaxf(lmax, sv);
  }
  for (int off = 32; off; off >>= 1) lmax = fmaxf(lmax, __shfl_xor(lmax, off));
  if ((tid & 63) == 0) sred[tid >> 6] = lmax;
  __syncthreads();
  const float m = fmaxf(fmaxf(sred[0], sred[1]), fmaxf(sred[2], sred[3]));
  __syncthreads();

  float lsum = 0.f;
#pragma unroll
  for (int i = 0; i < 4; ++i) {
    int l = i * 256 + tid;
    float p = __expf(sp[l] - m);
    sp[l] = p;
    lsum += p;
  }
  for (int off = 32; off; off >>= 1) lsum += __shfl_xor(lsum, off);
  if ((tid & 63) == 0) sred[tid >> 6] = lsum;
  __syncthreads();
  const float denom = sred[0] + sred[1] + sred[2] + sred[3];

  const int d = tid & 127, half = tid >> 7;
  float o = 0.f;
  for (int l = half; l < ctx; l += 2) {
    float p = sp[l];
    float v;
    if (l == ctx - 1) {
      v = bf2f(qkv[(size_t)tq * QKVN + 2 * DIMC + h * DC + d]);
    } else {
      int blk = btab[b * MAXBC + (l >> 4)];
      v = vheap[(((size_t)blk * 16 + (l & 15)) * HC + h) * DC + d];
    }
    o += p * v;
  }
  if (half) obuf[d] = o;
  __syncthreads();
  if (!half)
    attnb[(size_t)tq * DIMC + h * DC + d] = f2bf((o + obuf[d]) / denom);
}

// ---------------- SiLU(g) * u ----------------
__global__ __launch_bounds__(256) void silu_mul(
    const unsigned short* __restrict__ gu, unsigned short* __restrict__ act)
{
  size_t chunk = (size_t)blockIdx.x * 256 + threadIdx.x;
  size_t row = chunk >> 11;
  int c = (int)(chunk & 2047) << 3;
  const unsigned short* g = gu + row * (2 * FFNC) + c;
  u16x8 gv = *(const u16x8*)g;
  u16x8 uv = *(const u16x8*)(g + FFNC);
  u16x8 o;
#pragma unroll
  for (int i = 0; i < 8; ++i) {
    float gf = bf2f(gv[i]);
    float uf = bf2f(uv[i]);
    float sf = gf / (1.f + __expf(-gf));
    o[i] = f2bf(sf * uf);
  }
  *(u16x8*)(act + row * FFNC + c) = o;
}

// ---------------- launch ----------------
extern "C" void kernel_launch(void* const* d_in, const int* in_sizes, int n_in,
                              void* d_out, int out_size, void* d_ws, size_t ws_size,
                              hipStream_t stream) {
  const float* x     = (const float*)d_in[0];
  const float* kheap = (const float*)d_in[1];
  const float* vheap = (const float*)d_in[2];
  const int*   btab  = (const int*)d_in[4];
  const int*   ctxl  = (const int*)d_in[5];
  const float* n1w   = (const float*)d_in[10];
  const float* n2w   = (const float*)d_in[11];
  const float* wqkv  = (const float*)d_in[12];
  const float* wo    = (const float*)d_in[13];
  const float* wgu   = (const float*)d_in[14];
  const float* w2    = (const float*)d_in[15];
  float* out = (float*)d_out;

  // workspace layout:
  //   base region (269,484,032 B): xn | qkv(alias act) | attn | h_f32 | gu
  //   bf16 weights (536,870,912 B) if ws_size permits
  char* ws = (char*)d_ws;
  unsigned short* xn   = (unsigned short*)(ws);
  unsigned short* qkvb = (unsigned short*)(ws + 16842752);
  unsigned short* actb = qkvb;
  unsigned short* attn = (unsigned short*)(ws + 16842752 + 67371008);
  float*          hbuf = (float*)(ws + 16842752 + 67371008 + 16842752);
  unsigned short* gub  = (unsigned short*)(ws + 16842752 + 67371008 + 16842752 + 33685504);

  const size_t wbase = 269484032;
  const bool bw = ws_size >= wbase + 536870912ull;
  unsigned short* wqkv_h = (unsigned short*)(ws + wbase);
  unsigned short* wo_h   = (unsigned short*)(ws + wbase + 100663296);
  unsigned short* wgu_h  = (unsigned short*)(ws + wbase + 100663296 + 33554432);
  unsigned short* w2_h   = (unsigned short*)(ws + wbase + 100663296 + 33554432 + 268435456);

  if (bw) {
    cvt_w<<<2048, 256, 0, stream>>>(wqkv, wqkv_h, (long)QKVN * DIMC / 8);
    cvt_w<<<2048, 256, 0, stream>>>(wo,   wo_h,   (long)DIMC * DIMC / 8);
    cvt_w<<<2048, 256, 0, stream>>>(wgu,  wgu_h,  (long)2 * FFNC * DIMC / 8);
    cvt_w<<<2048, 256, 0, stream>>>(w2,   w2_h,   (long)DIMC * FFNC / 8);
  }

  const int nM = 17;  // ceil(2056/128)

  // 1. xn = rmsnorm(x) * n1w
  rmsnorm_k<<<TOKC, 256, 0, stream>>>(x, n1w, xn);
  // 2. qkv = xn @ wqkv^T (bf16 out)
  if (bw) gemm_bt<2,1><<<nM * (QKVN/128), 256, 0, stream>>>(xn, nullptr, wqkv_h, nullptr, qkvb, nullptr, TOKC, QKVN, DIMC);
  else    gemm_bt<2,0><<<nM * (QKVN/128), 256, 0, stream>>>(xn, wqkv, nullptr, nullptr, qkvb, nullptr, TOKC, QKVN, DIMC);
  // 3. prefill attention
  prefill_attn<<<dim3(HC, PSEQC / 64, 2), 256, 0, stream>>>(qkvb, attn);
  // 4. decode attention
  decode_attn<<<dim3(HC, BDC), 256, 0, stream>>>(qkvb, kheap, vheap, btab, ctxl, attn);
  // 5. h = attn @ wo^T + x
  if (bw) gemm_bt<1,1><<<nM * (DIMC/128), 256, 0, stream>>>(attn, nullptr, wo_h, hbuf, nullptr, x, TOKC, DIMC, DIMC);
  else    gemm_bt<1,0><<<nM * (DIMC/128), 256, 0, stream>>>(attn, wo, nullptr, hbuf, nullptr, x, TOKC, DIMC, DIMC);
  // 6. xn2 = rmsnorm(h) * n2w
  rmsnorm_k<<<TOKC, 256, 0, stream>>>(hbuf, n2w, xn);
  // 7. gu = xn2 @ wgu^T (bf16 out)
  if (bw) gemm_bt<2,1><<<nM * (2*FFNC/128), 256, 0, stream>>>(xn, nullptr, wgu_h, nullptr, gub, nullptr, TOKC, 2*FFNC, DIMC);
  else    gemm_bt<2,0><<<nM * (2*FFNC/128), 256, 0, stream>>>(xn, wgu, nullptr, nullptr, gub, nullptr, TOKC, 2*FFNC, DIMC);
  // 8. act = silu(g) * u
  silu_mul<<<(TOKC * (FFNC / 8)) / 256, 256, 0, stream>>>(gub, actb);
  // 9. out = act @ w2^T + h
  if (bw) gemm_bt<1,1><<<nM * (DIMC/128), 256, 0, stream>>>(actb, nullptr, w2_h, out, nullptr, hbuf, TOKC, DIMC, FFNC);
  else    gemm_bt<1,0><<<nM * (DIMC/128), 256, 0, stream>>>(actb, w2, nullptr, out, nullptr, hbuf, TOKC, DIMC, FFNC);
}

// Round 4
// 2016.930 us; speedup vs baseline: 1.7025x; 1.0723x over previous
//
#include <hip/hip_runtime.h>
#include <hip/hip_bf16.h>
#include <stdint.h>

// ---------------- problem constants (fixed by setup_inputs) ----------------
#define DIMC   4096
#define HC     32
#define DC     128
#define TPC    2048      // prefill tokens
#define TOKC   2056      // total tokens
#define BDC    8         // decode batch
#define MAXBC  64        // blocks per decode seq
#define PSEQC  1024      // prefill seq len (2 seqs)
#define QKVN   12288     // 3*H*D
#define FFNC   16384     // 4*DIM
#define PSCALE 0.08838834764831843f  // 1/sqrt(128)

typedef __attribute__((ext_vector_type(8))) short short8;
typedef __attribute__((ext_vector_type(4))) float f32x4;
typedef __attribute__((ext_vector_type(4))) unsigned short u16x4;
typedef __attribute__((ext_vector_type(8))) unsigned short u16x8;

__device__ inline unsigned short f2bf(float f) {   // f32 -> bf16 RNE
  union { float f; unsigned u; } v; v.f = f;
  unsigned r = v.u + 0x7FFFu + ((v.u >> 16) & 1u);
  return (unsigned short)(r >> 16);
}
__device__ inline float bf2f(unsigned short u) {
  union { unsigned u; float f; } v; v.u = ((unsigned)u) << 16;
  return v.f;
}
__device__ inline f32x4 mfma16(short8 a, short8 b, f32x4 c) {
  return __builtin_amdgcn_mfma_f32_16x16x32_bf16(a, b, c, 0, 0, 0);
}
__device__ inline void gload16(const void* g, void* l) {
  __builtin_amdgcn_global_load_lds(
      (const __attribute__((address_space(1))) void*)g,
      (__attribute__((address_space(3))) void*)l, 16, 0, 0);
}

// ---------------- weight convert f32 -> bf16 ----------------
__global__ __launch_bounds__(256) void cvt_w(
    const float* __restrict__ in, unsigned short* __restrict__ out, long n8)
{
  long i = (long)blockIdx.x * 256 + threadIdx.x;
  const long stride = (long)gridDim.x * 256;
  for (; i < n8; i += stride) {
    f32x4 a = ((const f32x4*)in)[2 * i];
    f32x4 b = ((const f32x4*)in)[2 * i + 1];
    u16x8 o;
#pragma unroll
    for (int j = 0; j < 4; ++j) { o[j] = f2bf(a[j]); o[j + 4] = f2bf(b[j]); }
    ((u16x8*)out)[i] = o;
  }
}

// ---------------- RMSNorm: f32 in -> bf16 out ----------------
__global__ __launch_bounds__(256) void rmsnorm_k(
    const float* __restrict__ x, const float* __restrict__ w,
    unsigned short* __restrict__ out)
{
  const int row = blockIdx.x;
  const int tid = threadIdx.x;
  const f32x4* xr = (const f32x4*)(x + (size_t)row * DIMC);
  f32x4 v[4];
  float ss = 0.f;
#pragma unroll
  for (int i = 0; i < 4; ++i) {
    v[i] = xr[i * 256 + tid];
    ss += v[i][0]*v[i][0] + v[i][1]*v[i][1] + v[i][2]*v[i][2] + v[i][3]*v[i][3];
  }
  for (int off = 32; off; off >>= 1) ss += __shfl_xor(ss, off);
  __shared__ float sred[4];
  if ((tid & 63) == 0) sred[tid >> 6] = ss;
  __syncthreads();
  const float rms = rsqrtf((sred[0]+sred[1]+sred[2]+sred[3]) * (1.f/DIMC) + 1e-5f);
  const f32x4* wr = (const f32x4*)w;
#pragma unroll
  for (int i = 0; i < 4; ++i) {
    f32x4 wv = wr[i * 256 + tid];
    u16x4 o;
#pragma unroll
    for (int j = 0; j < 4; ++j) o[j] = f2bf(v[i][j] * rms * wv[j]);
    *(u16x4*)(out + (size_t)row * DIMC + (size_t)(i * 256 + tid) * 4) = o;
  }
}

// ============ 8-phase 256x256 GEMM (T2+T3+T4+T5), bf16 B ============
// C[M,N] = A_bf16[M,K] @ B_bf16[N,K]^T (+Res).  MODE 1: f32 out + Res;
// MODE 2: bf16 out.  512 thr = 8 waves (2x4); per-wave out 128x64.
// LDS 128 KB: 2 buffers x {A0,A1,B0,B1} halves (16 KB each, [128][64] bf16,
// XOR-swizzle byte^=(row&7)<<4, staged via global_load_lds w/ pre-swizzled src).
// Phase order per K-tile: (A0,B0)(A0,B1)(A1,B1)(A1,B0); each phase stages one
// dead half of a future tile.
// vmcnt ledger (verified): entering iter t, tiles <=t landed, t+1{A0,B0,B1}
// in flight (6). q0..q3 add t+1.A1, t+2.A0, t+2.B0, t+2.B1 -> 14; q3 vmcnt(6)
// completes the 8 oldest = tile t+1 exactly. TAIL: when t+2 stages are
// skipped (t+2>=NT) only 8 are outstanding -> vmcnt(6) under-drains (the R3
// race: last K-tile read stale LDS). Fix: drain vmcnt(0) at those boundaries.
template<int MODE>
__global__ __launch_bounds__(512, 2) void gemm8p(
    const unsigned short* __restrict__ A, const unsigned short* __restrict__ Bh,
    float* __restrict__ Cf, unsigned short* __restrict__ Cb,
    const float* __restrict__ Res, int M, int N, int K)
{
  __shared__ char ldsc[131072];
  const int tid = threadIdx.x;
  const int lane = tid & 63, wid = tid >> 6;
  const int wr = wid >> 2, wc = wid & 3;
  const int lhi = lane >> 4, llo = lane & 15;

  // tile mapping: bijective XCD chunking, M-fast
  const int nM = (M + 255) >> 8;
  const int nwg = gridDim.x, orig = blockIdx.x;
  const int qq = nwg >> 3, rr = nwg & 7;
  const int xcd = orig & 7, lid = orig >> 3;
  const int wgid = (xcd < rr ? xcd*(qq+1) : rr*(qq+1) + (xcd-rr)*qq) + lid;
  const int bm = (wgid % nM) << 8;
  const int bn = (wgid / nM) << 8;

  // staging sources: slot s=i*512+tid -> row=s>>3, stored chunk (s&7),
  // holding logical chunk (s&7)^(row&7)  (read-side XOR matches)
  const unsigned short* src[2][2][2];  // [op A/B][half][issue]
#pragma unroll
  for (int i = 0; i < 2; ++i) {
    int s = i * 512 + tid;
    int row = s >> 3;
    int chunk = (s & 7) ^ (row & 7);
#pragma unroll
    for (int h = 0; h < 2; ++h) {
      int ga = bm + h * 128 + row; ga = ga < M ? ga : M - 1;
      src[0][h][i] = A  + (size_t)ga * K + chunk * 8;
      src[1][h][i] = Bh + (size_t)(bn + h * 128 + row) * K + chunk * 8;
    }
  }
  const int NT = K >> 6;

#define STG(U, OP, H) do { \
    int bb_ = (((U) & 1) << 16) + ((OP) << 15) + ((H) << 14) + (wid << 10); \
    gload16(src[OP][H][0] + ((size_t)(U) << 6), ldsc + bb_); \
    gload16(src[OP][H][1] + ((size_t)(U) << 6), ldsc + bb_ + 8192); \
  } while (0)

#define LDA(PB, HA) do { _Pragma("unroll") for (int m_ = 0; m_ < 4; ++m_) { \
    int row_ = wr*64 + m_*16 + llo; \
    int rb_ = (PB) + ((HA) << 14) + row_*128; int sx_ = (row_ & 7) << 4; \
    ar[m_][0] = *(const short8*)(ldsc + rb_ + ((lhi*16) ^ sx_)); \
    ar[m_][1] = *(const short8*)(ldsc + rb_ + ((64 + lhi*16) ^ sx_)); } } while (0)

#define LDB(PB, HB, DST) do { _Pragma("unroll") for (int n_ = 0; n_ < 2; ++n_) { \
    int row_ = wc*32 + n_*16 + llo; \
    int rb_ = (PB) + 32768 + ((HB) << 14) + row_*128; int sx_ = (row_ & 7) << 4; \
    DST[n_][0] = *(const short8*)(ldsc + rb_ + ((lhi*16) ^ sx_)); \
    DST[n_][1] = *(const short8*)(ldsc + rb_ + ((64 + lhi*16) ^ sx_)); } } while (0)

#define MM(QA, QB, B_) do { __builtin_amdgcn_s_setprio(1); \
    _Pragma("unroll") for (int m_ = 0; m_ < 4; ++m_) \
    _Pragma("unroll") for (int n_ = 0; n_ < 2; ++n_) { \
      acc[QA][QB][m_][n_] = mfma16(ar[m_][0], B_[n_][0], acc[QA][QB][m_][n_]); \
      acc[QA][QB][m_][n_] = mfma16(ar[m_][1], B_[n_][1], acc[QA][QB][m_][n_]); } \
    __builtin_amdgcn_s_setprio(0); } while (0)

#define WAITL do { asm volatile("s_waitcnt lgkmcnt(0)" ::: "memory"); \
    __builtin_amdgcn_sched_barrier(0); } while (0)
#define BAR __builtin_amdgcn_s_barrier()

  f32x4 acc[2][2][4][2] = {};
  short8 ar[4][2], b0[2][2], b1[2][2];

  // prologue: t0 fully + t1 {A0,B0,B1}; wait t0 landed (3 halves in flight)
  STG(0, 0, 0); STG(0, 0, 1); STG(0, 1, 0); STG(0, 1, 1);
  STG(1, 0, 0); STG(1, 1, 0); STG(1, 1, 1);
  asm volatile("s_waitcnt vmcnt(6)" ::: "memory");
  BAR;

  for (int t = 0; t < NT; ++t) {
    const int pb = (t & 1) << 16;
    // q0: (A0,B0); stage (t+1).A1 (other buffer, dead since q2 of t-1)
    LDA(pb, 0); LDB(pb, 0, b0);
    if (t + 1 < NT) STG(t + 1, 0, 1);
    BAR; WAITL;
    MM(0, 0, b0);
    BAR;
    // q1: (A0,B1); stage (t+2).A0 (this buffer, A0 dead after q0)
    LDB(pb, 1, b1);
    if (t + 2 < NT) STG(t + 2, 0, 0);
    BAR; WAITL;
    MM(0, 1, b1);
    BAR;
    // q2: (A1,B1); stage (t+2).B0 (B0 LDS dead after q0; kept in regs)
    LDA(pb, 1);
    if (t + 2 < NT) STG(t + 2, 1, 0);
    BAR; WAITL;
    MM(1, 1, b1);
    BAR;
    // q3: (A1,B0); stage (t+2).B1 (dead after q1); counted vmcnt at boundary.
    // TAIL FIX: when t+2 stages were skipped, drain fully (tile t+1 = last
    // tile's halves are among the <=8 outstanding and MUST land now).
    if (t + 2 < NT) {
      STG(t + 2, 1, 1);
      asm volatile("s_waitcnt vmcnt(6)" ::: "memory");
    } else {
      asm volatile("s_waitcnt vmcnt(0)" ::: "memory");
    }
    BAR;
    __builtin_amdgcn_sched_barrier(0);
    MM(1, 0, b0);
    BAR;
  }

  // epilogue: C/D layout col=lane&15, row=(lane>>4)*4+j
#pragma unroll
  for (int qa = 0; qa < 2; ++qa)
#pragma unroll
  for (int m_ = 0; m_ < 4; ++m_)
#pragma unroll
  for (int j = 0; j < 4; ++j) {
    int row = bm + qa*128 + wr*64 + m_*16 + lhi*4 + j;
    if (row < M) {
#pragma unroll
      for (int qb = 0; qb < 2; ++qb)
#pragma unroll
      for (int n_ = 0; n_ < 2; ++n_) {
        int col = bn + qb*128 + wc*32 + n_*16 + llo;
        float v = acc[qa][qb][m_][n_][j];
        if (MODE == 1) { v += Res[(size_t)row*N + col]; Cf[(size_t)row*N + col] = v; }
        else Cb[(size_t)row*N + col] = f2bf(v);
      }
    }
  }
#undef STG
#undef LDA
#undef LDB
#undef MM
#undef WAITL
#undef BAR
}

// ---------------- 128x128 2-barrier GEMM (kept for wo + f32 fallback) -------
template<int MODE, int BF16B>
__global__ __launch_bounds__(256) void gemm_bt(
    const unsigned short* __restrict__ A, const float* __restrict__ Bf,
    const unsigned short* __restrict__ Bh,
    float* __restrict__ Cf, unsigned short* __restrict__ Cb,
    const float* __restrict__ Res, int M, int N, int K)
{
  __shared__ unsigned short la[128 * 64];
  __shared__ unsigned short lb[128 * 64];
  const int tid = threadIdx.x;
  const int lane = tid & 63, wid = tid >> 6;
  const int wr = wid >> 1, wc = wid & 1;
  const int lhi = lane >> 4, llo = lane & 15;

  const int nM = (M + 127) >> 7;
  const int nwg = gridDim.x;
  const int orig = blockIdx.x;
  const int qq = nwg >> 3, rr = nwg & 7;
  const int xcd = orig & 7, lid = orig >> 3;
  const int wgid = (xcd < rr ? xcd * (qq + 1) : rr * (qq + 1) + (xcd - rr) * qq) + lid;
  const int bm = (wgid % nM) * 128;
  const int bn = (wgid / nM) * 128;

  const unsigned short* aSrc[4];
  const unsigned short* bSrcH[4];
  char* aDst[4];
  char* bDst[4];
#pragma unroll
  for (int p = 0; p < 4; ++p) {
    int slot = p * 256 + tid;
    int row = slot >> 3;
    int chunk = (slot & 7) ^ (row & 7);
    int gr = bm + row; gr = gr < M ? gr : M - 1;
    aSrc[p] = A + (size_t)gr * K + chunk * 8;
    aDst[p] = (char*)la + p * 4096 + wid * 1024;
    if (BF16B) {
      bSrcH[p] = Bh + (size_t)(bn + row) * K + chunk * 8;
      bDst[p] = (char*)lb + p * 4096 + wid * 1024;
    }
  }

  f32x4 acc[4][4] = {};

  for (int k0 = 0; k0 < K; k0 += 64) {
#pragma unroll
    for (int p = 0; p < 4; ++p) gload16(aSrc[p] + k0, aDst[p]);
    if (BF16B) {
#pragma unroll
      for (int p = 0; p < 4; ++p) gload16(bSrcH[p] + k0, bDst[p]);
    } else {
#pragma unroll
      for (int p = 0; p < 4; ++p) {
        int idx = p * 256 + tid;
        int row = idx >> 3, c8 = (idx & 7) << 3;
        const float* srcf = Bf + (size_t)(bn + row) * K + k0 + c8;
        f32x4 v0 = *(const f32x4*)srcf;
        f32x4 v1 = *(const f32x4*)(srcf + 4);
        short8 bv;
#pragma unroll
        for (int i = 0; i < 4; ++i) { bv[i] = (short)f2bf(v0[i]); bv[i+4] = (short)f2bf(v1[i]); }
        int byt = (row << 7) + (c8 << 1);
        byt ^= (row & 7) << 4;
        *(short8*)((char*)lb + byt) = bv;
      }
    }
    __syncthreads();
#pragma unroll
    for (int kk = 0; kk < 64; kk += 32) {
      short8 af[4], bfr[4];
#pragma unroll
      for (int m = 0; m < 4; ++m) {
        int row = wr * 64 + m * 16 + llo;
        int byt = (row << 7) + ((kk + lhi * 8) << 1);
        byt ^= (row & 7) << 4;
        af[m] = *(const short8*)((const char*)la + byt);
      }
#pragma unroll
      for (int n = 0; n < 4; ++n) {
        int row = wc * 64 + n * 16 + llo;
        int byt = (row << 7) + ((kk + lhi * 8) << 1);
        byt ^= (row & 7) << 4;
        bfr[n] = *(const short8*)((const char*)lb + byt);
      }
#pragma unroll
      for (int m = 0; m < 4; ++m)
#pragma unroll
        for (int n = 0; n < 4; ++n)
          acc[m][n] = mfma16(af[m], bfr[n], acc[m][n]);
    }
    __syncthreads();
  }

#pragma unroll
  for (int m = 0; m < 4; ++m) {
#pragma unroll
    for (int j = 0; j < 4; ++j) {
      int row = bm + wr * 64 + m * 16 + lhi * 4 + j;
      if (row < M) {
#pragma unroll
        for (int n = 0; n < 4; ++n) {
          int col = bn + wc * 64 + n * 16 + llo;
          float v = acc[m][n][j];
          if (MODE == 1) {
            v += Res[(size_t)row * N + col];
            Cf[(size_t)row * N + col] = v;
          } else {
            Cb[(size_t)row * N + col] = f2bf(v);
          }
        }
      }
    }
  }
}

// ---------------- Prefill flash attention (causal, per-seq) ----------------
__global__ __launch_bounds__(256) void prefill_attn(
    const unsigned short* __restrict__ qkv, unsigned short* __restrict__ attnb)
{
  const int h = blockIdx.x, qt = blockIdx.y, s = blockIdx.z;
  const int seq0 = s * PSEQC;
  const int q0 = qt * 64;
  const int tid = threadIdx.x;
  const int lane = tid & 63, w = tid >> 6;
  const int lhi = lane >> 4, llo = lane & 15;

  __shared__ unsigned short lk[64 * 128];
  __shared__ unsigned short lvt[128 * 72];
  __shared__ unsigned short lp[4][16 * 72];

  short8 qf[4];
  {
    const unsigned short* qrow =
        qkv + (size_t)(seq0 + q0 + w * 16 + llo) * QKVN + h * DC;
#pragma unroll
    for (int kk = 0; kk < 4; ++kk)
      qf[kk] = *(const short8*)(qrow + kk * 32 + lhi * 8);
  }

  float m_r[4], l_r[4];
#pragma unroll
  for (int r = 0; r < 4; ++r) { m_r[r] = -1e30f; l_r[r] = 0.f; }
  f32x4 oacc[8] = {};

  const int ntiles = qt + 1;
  for (int t = 0; t < ntiles; ++t) {
    const int j0 = t * 64;
#pragma unroll
    for (int p = 0; p < 4; ++p) {
      int idx = p * 256 + tid;
      int row = idx >> 4, c8 = (idx & 15) << 3;
      short8 kv = *(const short8*)(qkv + (size_t)(seq0 + j0 + row) * QKVN + DIMC + h * DC + c8);
      *(short8*)(lk + row * 128 + (c8 ^ ((row & 7) << 3))) = kv;
    }
#pragma unroll
    for (int p = 0; p < 4; ++p) {
      int idx = p * 256 + tid;
      int j = idx >> 4, c8 = (idx & 15) << 3;
      short8 vv = *(const short8*)(qkv + (size_t)(seq0 + j0 + j) * QKVN + 2 * DIMC + h * DC + c8);
#pragma unroll
      for (int i = 0; i < 8; ++i) {
        int d = c8 + i;
        int jj = j ^ (((d >> 3) & 7) << 3);
        lvt[d * 72 + jj] = (unsigned short)vv[i];
      }
    }
    __syncthreads();

    f32x4 sfr[4] = {};
#pragma unroll
    for (int n = 0; n < 4; ++n) {
      int row = n * 16 + llo;
#pragma unroll
      for (int kk = 0; kk < 4; ++kk) {
        int col = (kk * 32 + lhi * 8) ^ ((row & 7) << 3);
        short8 kf = *(const short8*)(lk + row * 128 + col);
        sfr[n] = mfma16(qf[kk], kf, sfr[n]);
      }
    }

    const bool diag = (t == ntiles - 1);
    const int qbase = q0 + w * 16 + lhi * 4;
    float pv[4][4];
#pragma unroll
    for (int r = 0; r < 4; ++r) {
      float mx = -1e30f;
#pragma unroll
      for (int n = 0; n < 4; ++n) {
        float sv = sfr[n][r] * PSCALE;
        if (diag && (j0 + n * 16 + llo > qbase + r)) sv = -1e30f;
        pv[n][r] = sv;
        mx = fmaxf(mx, sv);
      }
      for (int off = 8; off; off >>= 1) mx = fmaxf(mx, __shfl_xor(mx, off));
      float mnew = fmaxf(m_r[r], mx);
      float alpha = __expf(m_r[r] - mnew);
      m_r[r] = mnew;
      float rs = 0.f;
#pragma unroll
      for (int n = 0; n < 4; ++n) {
        float p = __expf(pv[n][r] - mnew);
        pv[n][r] = p;
        rs += p;
      }
      for (int off = 8; off; off >>= 1) rs += __shfl_xor(rs, off);
      l_r[r] = l_r[r] * alpha + rs;
#pragma unroll
      for (int f = 0; f < 8; ++f) oacc[f][r] *= alpha;
    }

    unsigned short* lpw = lp[w];
#pragma unroll
    for (int r = 0; r < 4; ++r)
#pragma unroll
      for (int n = 0; n < 4; ++n)
        lpw[(lhi * 4 + r) * 72 + n * 16 + llo] = f2bf(pv[n][r]);

#pragma unroll
    for (int kk = 0; kk < 2; ++kk) {
      short8 pf = *(const short8*)(lpw + llo * 72 + kk * 32 + lhi * 8);
#pragma unroll
      for (int f = 0; f < 8; ++f) {
        int d = f * 16 + llo;
        int jb = kk * 32 + lhi * 8;
        int jj = jb ^ (((d >> 3) & 7) << 3);
        short8 vf = *(const short8*)(lvt + d * 72 + jj);
        oacc[f] = mfma16(pf, vf, oacc[f]);
      }
    }
    __syncthreads();
  }

#pragma unroll
  for (int r = 0; r < 4; ++r) {
    int row = seq0 + q0 + w * 16 + lhi * 4 + r;
    float inv = 1.f / l_r[r];
#pragma unroll
    for (int f = 0; f < 8; ++f)
      attnb[(size_t)row * DIMC + h * DC + f * 16 + llo] = f2bf(oacc[f][r] * inv);
  }
}

// ---------------- Decode attention (paged KV, fresh-kv override) ------------
__global__ __launch_bounds__(256) void decode_attn(
    const unsigned short* __restrict__ qkv,
    const float* __restrict__ kheap, const float* __restrict__ vheap,
    const int* __restrict__ btab, const int* __restrict__ ctxl,
    unsigned short* __restrict__ attnb)
{
  const int h = blockIdx.x, b = blockIdx.y;
  const int ctx = ctxl[b];
  const int tq = TPC + b;
  const int tid = threadIdx.x;
  __shared__ float sq[DC];
  __shared__ float sp[1024];
  __shared__ float sred[4];
  __shared__ float obuf[DC];

  const unsigned short* qrow = qkv + (size_t)tq * QKVN + h * DC;
  if (tid < DC) sq[tid] = bf2f(qrow[tid]);
  __syncthreads();

  float lmax = -1e30f;
#pragma unroll
  for (int i = 0; i < 4; ++i) {
    int l = i * 256 + tid;
    float sv = -1e30f;
    if (l < ctx) {
      float accd = 0.f;
      if (l == ctx - 1) {
        const unsigned short* kn = qkv + (size_t)tq * QKVN + DIMC + h * DC;
        for (int d = 0; d < DC; ++d) accd += sq[d] * bf2f(kn[d]);
      } else {
        int blk = btab[b * MAXBC + (l >> 4)];
        const float* kp = kheap + (((size_t)blk * 16 + (l & 15)) * HC + h) * DC;
#pragma unroll
        for (int d = 0; d < DC; d += 4) {
          f32x4 kv = *(const f32x4*)(kp + d);
          accd += sq[d] * kv[0] + sq[d+1] * kv[1] + sq[d+2] * kv[2] + sq[d+3] * kv[3];
        }
      }
      sv = accd * PSCALE;
    }
    sp[l] = sv;
    lmax = fmaxf(lmax, sv);
  }
  for (int off = 32; off; off >>= 1) lmax = fmaxf(lmax, __shfl_xor(lmax, off));
  if ((tid & 63) == 0) sred[tid >> 6] = lmax;
  __syncthreads();
  const float m = fmaxf(fmaxf(sred[0], sred[1]), fmaxf(sred[2], sred[3]));
  __syncthreads();

  float lsum = 0.f;
#pragma unroll
  for (int i = 0; i < 4; ++i) {
    int l = i * 256 + tid;
    float p = __expf(sp[l] - m);
    sp[l] = p;
    lsum += p;
  }
  for (int off = 32; off; off >>= 1) lsum += __shfl_xor(lsum, off);
  if ((tid & 63) == 0) sred[tid >> 6] = lsum;
  __syncthreads();
  const float denom = sred[0] + sred[1] + sred[2] + sred[3];

  const int d = tid & 127, half = tid >> 7;
  float o = 0.f;
  for (int l = half; l < ctx; l += 2) {
    float p = sp[l];
    float v;
    if (l == ctx - 1) {
      v = bf2f(qkv[(size_t)tq * QKVN + 2 * DIMC + h * DC + d]);
    } else {
      int blk = btab[b * MAXBC + (l >> 4)];
      v = vheap[(((size_t)blk * 16 + (l & 15)) * HC + h) * DC + d];
    }
    o += p * v;
  }
  if (half) obuf[d] = o;
  __syncthreads();
  if (!half)
    attnb[(size_t)tq * DIMC + h * DC + d] = f2bf((o + obuf[d]) / denom);
}

// ---------------- SiLU(g) * u ----------------
__global__ __launch_bounds__(256) void silu_mul(
    const unsigned short* __restrict__ gu, unsigned short* __restrict__ act)
{
  size_t chunk = (size_t)blockIdx.x * 256 + threadIdx.x;
  size_t row = chunk >> 11;
  int c = (int)(chunk & 2047) << 3;
  const unsigned short* g = gu + row * (2 * FFNC) + c;
  u16x8 gv = *(const u16x8*)g;
  u16x8 uv = *(const u16x8*)(g + FFNC);
  u16x8 o;
#pragma unroll
  for (int i = 0; i < 8; ++i) {
    float gf = bf2f(gv[i]);
    float uf = bf2f(uv[i]);
    float sf = gf / (1.f + __expf(-gf));
    o[i] = f2bf(sf * uf);
  }
  *(u16x8*)(act + row * FFNC + c) = o;
}

// ---------------- launch ----------------
extern "C" void kernel_launch(void* const* d_in, const int* in_sizes, int n_in,
                              void* d_out, int out_size, void* d_ws, size_t ws_size,
                              hipStream_t stream) {
  const float* x     = (const float*)d_in[0];
  const float* kheap = (const float*)d_in[1];
  const float* vheap = (const float*)d_in[2];
  const int*   btab  = (const int*)d_in[4];
  const int*   ctxl  = (const int*)d_in[5];
  const float* n1w   = (const float*)d_in[10];
  const float* n2w   = (const float*)d_in[11];
  const float* wqkv  = (const float*)d_in[12];
  const float* wo    = (const float*)d_in[13];
  const float* wgu   = (const float*)d_in[14];
  const float* w2    = (const float*)d_in[15];
  float* out = (float*)d_out;

  char* ws = (char*)d_ws;
  unsigned short* xn   = (unsigned short*)(ws);
  unsigned short* qkvb = (unsigned short*)(ws + 16842752);
  unsigned short* actb = qkvb;
  unsigned short* attn = (unsigned short*)(ws + 16842752 + 67371008);
  float*          hbuf = (float*)(ws + 16842752 + 67371008 + 16842752);
  unsigned short* gub  = (unsigned short*)(ws + 16842752 + 67371008 + 16842752 + 33685504);

  const size_t wbase = 269484032;
  const bool bw = ws_size >= wbase + 536870912ull;
  unsigned short* wqkv_h = (unsigned short*)(ws + wbase);
  unsigned short* wo_h   = (unsigned short*)(ws + wbase + 100663296);
  unsigned short* wgu_h  = (unsigned short*)(ws + wbase + 100663296 + 33554432);
  unsigned short* w2_h   = (unsigned short*)(ws + wbase + 100663296 + 33554432 + 268435456);

  if (bw) {
    cvt_w<<<2048, 256, 0, stream>>>(wqkv, wqkv_h, (long)QKVN * DIMC / 8);
    cvt_w<<<2048, 256, 0, stream>>>(wo,   wo_h,   (long)DIMC * DIMC / 8);
    cvt_w<<<2048, 256, 0, stream>>>(wgu,  wgu_h,  (long)2 * FFNC * DIMC / 8);
    cvt_w<<<2048, 256, 0, stream>>>(w2,   w2_h,   (long)DIMC * FFNC / 8);
  }

  const int nM8 = 9;   // ceil(2056/256)
  const int nM4 = 17;  // ceil(2056/128)

  // 1. xn = rmsnorm(x) * n1w
  rmsnorm_k<<<TOKC, 256, 0, stream>>>(x, n1w, xn);
  // 2. qkv = xn @ wqkv^T (bf16 out)
  if (bw) gemm8p<2><<<nM8 * (QKVN/256), 512, 0, stream>>>(xn, wqkv_h, nullptr, qkvb, nullptr, TOKC, QKVN, DIMC);
  else    gemm_bt<2,0><<<nM4 * (QKVN/128), 256, 0, stream>>>(xn, wqkv, nullptr, nullptr, qkvb, nullptr, TOKC, QKVN, DIMC);
  // 3. prefill attention
  prefill_attn<<<dim3(HC, PSEQC / 64, 2), 256, 0, stream>>>(qkvb, attn);
  // 4. decode attention
  decode_attn<<<dim3(HC, BDC), 256, 0, stream>>>(qkvb, kheap, vheap, btab, ctxl, attn);
  // 5. h = attn @ wo^T + x   (small N -> keep 128^2 kernel for occupancy)
  if (bw) gemm_bt<1,1><<<nM4 * (DIMC/128), 256, 0, stream>>>(attn, nullptr, wo_h, hbuf, nullptr, x, TOKC, DIMC, DIMC);
  else    gemm_bt<1,0><<<nM4 * (DIMC/128), 256, 0, stream>>>(attn, wo, nullptr, hbuf, nullptr, x, TOKC, DIMC, DIMC);
  // 6. xn2 = rmsnorm(h) * n2w
  rmsnorm_k<<<TOKC, 256, 0, stream>>>(hbuf, n2w, xn);
  // 7. gu = xn2 @ wgu^T (bf16 out)
  if (bw) gemm8p<2><<<nM8 * (2*FFNC/256), 512, 0, stream>>>(xn, wgu_h, nullptr, gub, nullptr, TOKC, 2*FFNC, DIMC);
  else    gemm_bt<2,0><<<nM4 * (2*FFNC/128), 256, 0, stream>>>(xn, wgu, nullptr, nullptr, gub, nullptr, TOKC, 2*FFNC, DIMC);
  // 8. act = silu(g) * u
  silu_mul<<<(TOKC * (FFNC / 8)) / 256, 256, 0, stream>>>(gub, actb);
  // 9. out = act @ w2^T + h
  if (bw) gemm8p<1><<<nM8 * (DIMC/256), 512, 0, stream>>>(actb, w2_h, out, nullptr, hbuf, TOKC, DIMC, FFNC);
  else    gemm_bt<1,0><<<nM4 * (DIMC/128), 256, 0, stream>>>(actb, w2, nullptr, out, nullptr, hbuf, TOKC, DIMC, FFNC);
}